// Round 3
// baseline (249.030 us; speedup 1.0000x reference)
//
#include <hip/hip_runtime.h>
#include <hip/hip_bf16.h>
#include <cstdint>
#include <cstddef>

#define T_TOK 2048
#define HDIM  1024
#define FDIM  2048
#define NEXP  8

#define BM 128
#define BN 64
#define BK 32
#define MT1 (T_TOK / BM)    // 16 m-tiles (worst case)
#define NT1 (FDIM / BN)     // 32 n-tiles (gate/up)
#define NT2 (HDIM / BN)     // 16 n-tiles (down)
#define NK1 (HDIM / BK)     // 32 K-steps (gate/up)
#define NK2 (FDIM / BK)     // 64 K-steps (down)

typedef __attribute__((ext_vector_type(8))) short bf16x8;
typedef __attribute__((ext_vector_type(4))) float f32x4;

__device__ __forceinline__ unsigned short f2b(float f) {
  __hip_bfloat16 h = __float2bfloat16(f);
  return __builtin_bit_cast(unsigned short, h);
}

__device__ __forceinline__ void gload16(const void* g, void* l) {
  __builtin_amdgcn_global_load_lds(
      (const __attribute__((address_space(1))) unsigned int*)g,
      (__attribute__((address_space(3))) unsigned int*)l, 16, 0, 0);
}

__device__ __forceinline__ void pack_write(unsigned short* d, float4 a, float4 b) {
  union { unsigned short u[8]; uint4 v; } p;
  p.u[0] = f2b(a.x); p.u[1] = f2b(a.y); p.u[2] = f2b(a.z); p.u[3] = f2b(a.w);
  p.u[4] = f2b(b.x); p.u[5] = f2b(b.y); p.u[6] = f2b(b.z); p.u[7] = f2b(b.w);
  *(uint4*)d = p.v;
}

// ---------------- router + sparsemixer (eval) + x->bf16 ----------------
__global__ __launch_bounds__(256) void router_k(
    const float* __restrict__ x, const float* __restrict__ rw,
    float* __restrict__ wslot, int* __restrict__ rows,
    int* __restrict__ cnt, unsigned short* __restrict__ xb)
{
  const int wave = threadIdx.x >> 6, lane = threadIdx.x & 63;
  const int t = blockIdx.x * 4 + wave;
  const float* xr = x + (size_t)t * HDIM;
  unsigned short* xbr = xb + (size_t)t * HDIM;
  float acc[NEXP];
#pragma unroll
  for (int e = 0; e < NEXP; ++e) acc[e] = 0.f;
  for (int i = 0; i < HDIM / 64; ++i) {
    const int h = i * 64 + lane;
    const float xv = xr[h];
    xbr[h] = f2b(xv);
#pragma unroll
    for (int e = 0; e < NEXP; ++e) acc[e] += xv * rw[e * HDIM + h];
  }
#pragma unroll
  for (int e = 0; e < NEXP; ++e) {
#pragma unroll
    for (int off = 32; off; off >>= 1) acc[e] += __shfl_xor(acc[e], off);
  }
  if (lane == 0) {
    float m1 = acc[0]; int i1 = 0;
#pragma unroll
    for (int e = 1; e < NEXP; ++e) if (acc[e] > m1) { m1 = acc[e]; i1 = e; }
    float sum1 = 0.f;
#pragma unroll
    for (int e = 0; e < NEXP; ++e) {
      const float f = fmaxf(fabsf(acc[e]), m1);
      if (m1 - acc[e] <= 0.02f * f) sum1 += expf(acc[e] - m1);
    }
    float m2 = -3.4e38f; int i2 = 0;
#pragma unroll
    for (int e = 0; e < NEXP; ++e)
      if (e != i1 && acc[e] > m2) { m2 = acc[e]; i2 = e; }
    float sum2 = 0.f;
#pragma unroll
    for (int e = 0; e < NEXP; ++e) {
      if (e == i1) continue;
      const float f = fmaxf(fabsf(acc[e]), m2);
      if (m2 - acc[e] <= 0.02f * f) sum2 += expf(acc[e] - m2);
    }
    wslot[2 * t]     = 1.f / sum1;
    wslot[2 * t + 1] = 1.f / sum2;
    int p1 = atomicAdd(&cnt[i1], 1); rows[i1 * T_TOK + p1] = 2 * t;
    int p2 = atomicAdd(&cnt[i2], 1); rows[i2 * T_TOK + p2] = 2 * t + 1;
  }
}

// ---------------- gate/up GEMM: h = silu(x Wg^T) * (x Wu^T) * w ----------------
// A (gathered bf16 x rows) via global_load_lds; B (fp32 weights) via T14 split:
// issue loads before MFMA, cvt+ds_write after barrier. Double-buffered LDS.
__global__ __launch_bounds__(256) void gemm_gateup_k(
    const unsigned short* __restrict__ xb,
    const float* __restrict__ wg32, const float* __restrict__ wu32,
    const int* __restrict__ rows, const int* __restrict__ cnt,
    const float* __restrict__ wslot, unsigned short* __restrict__ hbuf)
{
  const int bx = blockIdx.x;
  const int e  = bx >> 9;          // / (MT1*NT1=512)
  const int rm = bx & 511;
  const int mt = rm >> 5;          // / NT1
  const int nt = rm & 31;
  const int cnt_e = cnt[e];
  if (mt * BM >= cnt_e) return;

  __shared__ unsigned short As[2][BM * BK];   // 2 x 8 KiB
  __shared__ unsigned short Bg[2][BN * BK];   // 2 x 4 KiB
  __shared__ unsigned short Bu[2][BN * BK];   // 2 x 4 KiB
  __shared__ int ldsRow[BM];

  const int tid = threadIdx.x;
  if (tid < BM) {
    const int idx = mt * BM + tid;
    ldsRow[tid] = (idx < cnt_e) ? rows[e * T_TOK + idx] : -1;
  }
  __syncthreads();

  const int lane = tid & 63, w = tid >> 6;
  const int wr = w >> 1, wc = w & 1;        // 2x2 wave grid; wave = 64(M) x 32(N), dual out
  const int lr = lane & 15, lq = lane >> 4;

  // A staging: wave w covers rows [w*16, w*16+16) and [64+w*16, ...), lane-linear 16B
  const int srow = lane >> 2;
  const int sk   = (lane & 3) * 8;
  int ra0 = ldsRow[w * 16 + srow];      if (ra0 < 0) ra0 = 0;
  int ra1 = ldsRow[64 + w * 16 + srow]; if (ra1 < 0) ra1 = 0;
  const unsigned short* aS0 = xb + (size_t)(ra0 >> 1) * HDIM + sk;
  const unsigned short* aS1 = xb + (size_t)(ra1 >> 1) * HDIM + sk;
  const int aOff0 = (w * 16) * BK + lane * 8;
  const int aOff1 = (64 + w * 16) * BK + lane * 8;

  // B reg staging: thread covers row tid>>2 (0..63), k-chunk (tid&3)*8
  const int frow = tid >> 2, fk = (tid & 3) * 8;
  const float* fgS = wg32 + ((size_t)e * FDIM + nt * BN + frow) * HDIM + fk;
  const float* fuS = wu32 + ((size_t)e * FDIM + nt * BN + frow) * HDIM + fk;
  const int bOff = frow * BK + fk;

  f32x4 accg[4][2], accu[4][2];
#pragma unroll
  for (int mf = 0; mf < 4; ++mf)
#pragma unroll
    for (int nf = 0; nf < 2; ++nf) {
      accg[mf][nf] = (f32x4){0.f, 0.f, 0.f, 0.f};
      accu[mf][nf] = (f32x4){0.f, 0.f, 0.f, 0.f};
    }

  // prologue: stage tile 0 into buffer 0
  {
    const float4 g0 = *(const float4*)(fgS);
    const float4 g1 = *(const float4*)(fgS + 4);
    const float4 u0 = *(const float4*)(fuS);
    const float4 u1 = *(const float4*)(fuS + 4);
    gload16(aS0, &As[0][aOff0]);
    gload16(aS1, &As[0][aOff1]);
    pack_write(&Bg[0][bOff], g0, g1);
    pack_write(&Bu[0][bOff], u0, u1);
  }
  __syncthreads();

  int cur = 0;
  for (int k = 0; k < NK1; ++k) {
    const int nxt = cur ^ 1;
    float4 ng0, ng1, nu0, nu1;
    const bool pf = (k + 1 < NK1);
    if (pf) {
      const int ko = (k + 1) * BK;
      ng0 = *(const float4*)(fgS + ko);
      ng1 = *(const float4*)(fgS + ko + 4);
      nu0 = *(const float4*)(fuS + ko);
      nu1 = *(const float4*)(fuS + ko + 4);
      gload16(aS0 + ko, &As[nxt][aOff0]);
      gload16(aS1 + ko, &As[nxt][aOff1]);
    }

    bf16x8 a[4], bg[2], bu[2];
#pragma unroll
    for (int mf = 0; mf < 4; ++mf)
      a[mf] = *(const bf16x8*)&As[cur][(wr * 64 + mf * 16 + lr) * BK + lq * 8];
#pragma unroll
    for (int nf = 0; nf < 2; ++nf) {
      bg[nf] = *(const bf16x8*)&Bg[cur][(wc * 32 + nf * 16 + lr) * BK + lq * 8];
      bu[nf] = *(const bf16x8*)&Bu[cur][(wc * 32 + nf * 16 + lr) * BK + lq * 8];
    }
#pragma unroll
    for (int mf = 0; mf < 4; ++mf)
#pragma unroll
      for (int nf = 0; nf < 2; ++nf) {
        accg[mf][nf] = __builtin_amdgcn_mfma_f32_16x16x32_bf16(a[mf], bg[nf], accg[mf][nf], 0, 0, 0);
        accu[mf][nf] = __builtin_amdgcn_mfma_f32_16x16x32_bf16(a[mf], bu[nf], accu[mf][nf], 0, 0, 0);
      }
    __syncthreads();   // drains vmcnt: A[nxt] landed, B regs ready

    if (pf) {
      pack_write(&Bg[nxt][bOff], ng0, ng1);
      pack_write(&Bu[nxt][bOff], nu0, nu1);
    }
    __syncthreads();
    cur = nxt;
  }

  // epilogue: h = silu(g)*u*w  (C/D frag: col=lane&15, row=(lane>>4)*4+i)
#pragma unroll
  for (int mf = 0; mf < 4; ++mf)
#pragma unroll
    for (int nf = 0; nf < 2; ++nf) {
      const int col = nt * BN + wc * 32 + nf * 16 + lr;
#pragma unroll
      for (int i = 0; i < 4; ++i) {
        const int lrow = wr * 64 + mf * 16 + lq * 4 + i;
        const int r = ldsRow[lrow];
        if (r < 0) continue;
        const float g = accg[mf][nf][i], u = accu[mf][nf][i];
        const float val = g / (1.f + __expf(-g)) * u * wslot[r];
        hbuf[(size_t)r * FDIM + col] = f2b(val);
      }
    }
}

// ---------------- down GEMM: obuf[slot] = h[slot] Wd^T (plain stores) ----------------
__global__ __launch_bounds__(256) void gemm_down_k(
    const unsigned short* __restrict__ hbuf,
    const float* __restrict__ wd32,
    const int* __restrict__ rows, const int* __restrict__ cnt,
    float* __restrict__ obuf)
{
  const int bx = blockIdx.x;
  const int e  = bx >> 8;          // / (MT1*NT2=256)
  const int rm = bx & 255;
  const int mt = rm >> 4;          // / NT2
  const int nt = rm & 15;
  const int cnt_e = cnt[e];
  if (mt * BM >= cnt_e) return;

  __shared__ unsigned short As[2][BM * BK];
  __shared__ unsigned short Bs[2][BN * BK];
  __shared__ int ldsRow[BM];

  const int tid = threadIdx.x;
  if (tid < BM) {
    const int idx = mt * BM + tid;
    ldsRow[tid] = (idx < cnt_e) ? rows[e * T_TOK + idx] : -1;
  }
  __syncthreads();

  const int lane = tid & 63, w = tid >> 6;
  const int wr = w >> 1, wc = w & 1;
  const int lr = lane & 15, lq = lane >> 4;

  const int srow = lane >> 2;
  const int sk   = (lane & 3) * 8;
  int ra0 = ldsRow[w * 16 + srow];      if (ra0 < 0) ra0 = 0;
  int ra1 = ldsRow[64 + w * 16 + srow]; if (ra1 < 0) ra1 = 0;
  const unsigned short* aS0 = hbuf + (size_t)ra0 * FDIM + sk;
  const unsigned short* aS1 = hbuf + (size_t)ra1 * FDIM + sk;
  const int aOff0 = (w * 16) * BK + lane * 8;
  const int aOff1 = (64 + w * 16) * BK + lane * 8;

  const int frow = tid >> 2, fk = (tid & 3) * 8;
  const float* fS = wd32 + ((size_t)e * HDIM + nt * BN + frow) * FDIM + fk;
  const int bOff = frow * BK + fk;

  f32x4 acc[4][2];
#pragma unroll
  for (int mf = 0; mf < 4; ++mf)
#pragma unroll
    for (int nf = 0; nf < 2; ++nf) acc[mf][nf] = (f32x4){0.f, 0.f, 0.f, 0.f};

  {
    const float4 b0 = *(const float4*)(fS);
    const float4 b1 = *(const float4*)(fS + 4);
    gload16(aS0, &As[0][aOff0]);
    gload16(aS1, &As[0][aOff1]);
    pack_write(&Bs[0][bOff], b0, b1);
  }
  __syncthreads();

  int cur = 0;
  for (int k = 0; k < NK2; ++k) {
    const int nxt = cur ^ 1;
    float4 nb0, nb1;
    const bool pf = (k + 1 < NK2);
    if (pf) {
      const int ko = (k + 1) * BK;
      nb0 = *(const float4*)(fS + ko);
      nb1 = *(const float4*)(fS + ko + 4);
      gload16(aS0 + ko, &As[nxt][aOff0]);
      gload16(aS1 + ko, &As[nxt][aOff1]);
    }

    bf16x8 a[4], b[2];
#pragma unroll
    for (int mf = 0; mf < 4; ++mf)
      a[mf] = *(const bf16x8*)&As[cur][(wr * 64 + mf * 16 + lr) * BK + lq * 8];
#pragma unroll
    for (int nf = 0; nf < 2; ++nf)
      b[nf] = *(const bf16x8*)&Bs[cur][(wc * 32 + nf * 16 + lr) * BK + lq * 8];
#pragma unroll
    for (int mf = 0; mf < 4; ++mf)
#pragma unroll
      for (int nf = 0; nf < 2; ++nf)
        acc[mf][nf] = __builtin_amdgcn_mfma_f32_16x16x32_bf16(a[mf], b[nf], acc[mf][nf], 0, 0, 0);
    __syncthreads();

    if (pf) pack_write(&Bs[nxt][bOff], nb0, nb1);
    __syncthreads();
    cur = nxt;
  }

#pragma unroll
  for (int mf = 0; mf < 4; ++mf)
#pragma unroll
    for (int nf = 0; nf < 2; ++nf) {
      const int col = nt * BN + wc * 32 + nf * 16 + lr;
#pragma unroll
      for (int i = 0; i < 4; ++i) {
        const int lrow = wr * 64 + mf * 16 + lq * 4 + i;
        const int r = ldsRow[lrow];
        if (r < 0) continue;
        obuf[(size_t)r * HDIM + col] = acc[mf][nf][i];
      }
    }
}

// ---------------- combine: out[t] = obuf[2t] + obuf[2t+1] ----------------
__global__ __launch_bounds__(256) void combine_k(const float* __restrict__ obuf,
                                                 float* __restrict__ out)
{
  const int i = blockIdx.x * 256 + threadIdx.x;   // over T_TOK*HDIM/4 float4s
  const int t = i >> 8, c = i & 255;
  const float4* o4 = (const float4*)obuf;
  const float4 a = o4[(size_t)(2 * t) * (HDIM / 4) + c];
  const float4 b = o4[(size_t)(2 * t + 1) * (HDIM / 4) + c];
  float4 r; r.x = a.x + b.x; r.y = a.y + b.y; r.z = a.z + b.z; r.w = a.w + b.w;
  ((float4*)out)[i] = r;
}

extern "C" void kernel_launch(void* const* d_in, const int* in_sizes, int n_in,
                              void* d_out, int out_size, void* d_ws, size_t ws_size,
                              hipStream_t stream) {
  const float* x  = (const float*)d_in[0];   // [2,1024,1024]
  const float* rw = (const float*)d_in[1];   // [8,1024]
  const float* wg = (const float*)d_in[2];   // [8,2048,1024]
  const float* wu = (const float*)d_in[3];   // [8,2048,1024]
  const float* wd = (const float*)d_in[4];   // [8,1024,2048]
  float* out = (float*)d_out;

  char* ws = (char*)d_ws;
  unsigned short* hbuf = (unsigned short*)ws;                        // 16 MiB
  unsigned short* xb   = (unsigned short*)(ws + (16u << 20));        // 4 MiB
  int*   cnt   = (int*)  (ws + (20u << 20));                         // 256 B
  int*   rows  = (int*)  (ws + (20u << 20) + 256);                   // 64 KiB
  float* wslot = (float*)(ws + (20u << 20) + 256 + 65536);           // 16 KiB
  float* obuf  = (float*)(ws + (24ull << 20));                       // 16 MiB

  hipMemsetAsync(cnt, 0, 256, stream);
  router_k<<<T_TOK / 4, 256, 0, stream>>>(x, rw, wslot, rows, cnt, xb);
  gemm_gateup_k<<<NEXP * MT1 * NT1, 256, 0, stream>>>(xb, wg, wu, rows, cnt, wslot, hbuf);
  gemm_down_k<<<NEXP * MT1 * NT2, 256, 0, stream>>>(hbuf, wd, rows, cnt, obuf);
  combine_k<<<T_TOK * HDIM / 4 / 256, 256, 0, stream>>>(obuf, out);
}